// Round 2
// baseline (296.148 us; speedup 1.0000x reference)
//
#include <hip/hip_runtime.h>
#include <stdint.h>

#define B 128
#define F 8192
#define H 8192
#define S 4
#define K 32
#define L 3
#define C 100

// ---------------------------------------------------------------------------
// Pack x (B,F) float {0,1} -> xT[f] = 128-bit mask over b (2 u64 words).
// Block = 128 threads (thread = b), each block handles 64 consecutive f.
// ---------------------------------------------------------------------------
__global__ void pack_x_kernel(const float* __restrict__ x, uint64_t* __restrict__ xT) {
    const int b = threadIdx.x;           // 0..127
    const int f0 = blockIdx.x * 64;
    for (int j = 0; j < 64; ++j) {
        const int f = f0 + j;
        const float v = x[(size_t)b * F + f];
        const uint64_t m = __ballot(v > 0.5f);   // per-wave 64-bit mask
        if ((threadIdx.x & 63) == 0)
            xT[(size_t)f * 2 + (threadIdx.x >> 6)] = m;
    }
}

__device__ __forceinline__ int load_threshold(const int* p) {
    // threshold is a tiny int; guard against the harness storing it as f32 bits
    int v = *p;
    if (v >= (1 << 23)) v = (int)__int_as_float(v);
    return v;
}

// ---------------------------------------------------------------------------
// One EISANI layer: prevT (Hprev x 128-bit) -> outT (H x 128-bit).
// One wave per neuron h; lane = batch (lane handles b=lane and b=lane+64).
// idx/sign are wave-uniform per (s,h,k): loaded by lanes<32, broadcast by shfl,
// then routed through readfirstlane so the column load is a scalar broadcast.
// ---------------------------------------------------------------------------
__global__ void layer_kernel(const ulonglong2* __restrict__ prevT,
                             const int* __restrict__ idx,
                             const float* __restrict__ signs,
                             uint64_t* __restrict__ outT,
                             const int* __restrict__ thrp) {
    const int lane = threadIdx.x & 63;
    const int h = blockIdx.x * 4 + (threadIdx.x >> 6);
    const int thr = load_threshold(thrp);

    bool f0 = false, f1 = false;
#pragma unroll
    for (int s = 0; s < S; ++s) {
        const int base = (s * H + h) * K;
        int packed = 0;
        if (lane < K) {
            const int ik = idx[base + lane];               // coalesced 128B
            const int neg = (signs[base + lane] < 0.0f) ? 1 : 0;
            packed = ik | (neg << 16);                     // ik < 8192 fits
        }
        int z0 = 0, z1 = 0;
#pragma unroll 8
        for (int k = 0; k < K; ++k) {
            const int p  = __builtin_amdgcn_readfirstlane(__shfl(packed, k, 64));
            const int ik = p & 0xFFFF;                     // wave-uniform (SGPR)
            const int sv = 1 - ((p >> 15) & 2);            // +1 / -1
            const ulonglong2 col = prevT[ik];              // uniform 16B load
            z0 += ((col.x >> lane) & 1ull) ? sv : 0;
            z1 += ((col.y >> lane) & 1ull) ? sv : 0;
        }
        f0 |= (z0 >= thr);
        f1 |= (z1 >= thr);
    }
    const uint64_t m0 = __ballot(f0);
    const uint64_t m1 = __ballot(f1);
    if (lane == 0) {
        outT[(size_t)h * 2]     = m0;
        outT[(size_t)h * 2 + 1] = m1;
    }
}

// ---------------------------------------------------------------------------
// Zero the output (harness poisons d_out before every launch).
// ---------------------------------------------------------------------------
__global__ void zero_out_kernel(float* __restrict__ out) {
    const int i = blockIdx.x * 256 + threadIdx.x;
    if (i < B * C) out[i] = 0.0f;
}

// ---------------------------------------------------------------------------
// out[b][c] = sum_l sum_h act[l][b][h] * wout[l][h][c], act in {0,1}.
// Block = 128 threads (thread = c, active c<100), handles 64 h for all l,b.
// LDS accumulator acc[128][100]; set-bit walk over the 128-bit column.
// ---------------------------------------------------------------------------
__global__ void final_kernel(const uint64_t* __restrict__ actT,
                             const float* __restrict__ wout,
                             float* __restrict__ out) {
    __shared__ float acc[B * C];                 // 51200 B
    const int c = threadIdx.x;
    for (int i = threadIdx.x; i < B * C; i += 128) acc[i] = 0.0f;
    __syncthreads();

    const int h0 = blockIdx.x * 64;
#pragma unroll
    for (int l = 0; l < L; ++l) {
        const uint64_t* aT = actT + (size_t)l * H * 2;
        const float* w = wout + ((size_t)l * H + h0) * C;
        for (int j = 0; j < 64; ++j) {
            const int h = h0 + j;
            const uint64_t m0 = aT[(size_t)h * 2];
            const uint64_t m1 = aT[(size_t)h * 2 + 1];
            if ((m0 | m1) == 0ull) continue;     // block-uniform skip (sparsity)
            const float wv = (c < C) ? w[(size_t)j * C + c] : 0.0f;
            uint64_t m = m0;
            while (m) {
                const int b = __ffsll((unsigned long long)m) - 1;
                m &= m - 1;
                if (c < C) acc[b * C + c] += wv;
            }
            m = m1;
            while (m) {
                const int b = 64 + __ffsll((unsigned long long)m) - 1;
                m &= m - 1;
                if (c < C) acc[b * C + c] += wv;
            }
        }
    }
    __syncthreads();
    if (c < C) {
        for (int b = 0; b < B; ++b)
            atomicAdd(&out[b * C + c], acc[b * C + c]);
    }
}

// ---------------------------------------------------------------------------
extern "C" void kernel_launch(void* const* d_in, const int* in_sizes, int n_in,
                              void* d_out, int out_size, void* d_ws, size_t ws_size,
                              hipStream_t stream) {
    const float* x      = (const float*)d_in[0];   // (B,F)
    const float* signs0 = (const float*)d_in[1];   // (S,H,K)
    const float* signsH = (const float*)d_in[2];   // (L-1,S,H,K)
    const float* wout   = (const float*)d_in[3];   // (L,H,C)
    const int*   idx0   = (const int*)d_in[4];     // (S,H,K)
    const int*   idxH   = (const int*)d_in[5];     // (L-1,S,H,K)
    const int*   thr    = (const int*)d_in[6];     // scalar
    float* out = (float*)d_out;                    // (B,C)

    // Workspace: xT (F*2 u64) then actT (L*H*2 u64) -> 512 KiB total.
    uint64_t* xT   = (uint64_t*)d_ws;
    uint64_t* actT = xT + (size_t)F * 2;

    pack_x_kernel<<<F / 64, 128, 0, stream>>>(x, xT);

    // layer 0: from xT with idx0/signs0
    layer_kernel<<<H / 4, 256, 0, stream>>>((const ulonglong2*)xT, idx0, signs0,
                                            actT, thr);
    // layer 1: from actT[0] with idxH[0]/signsH[0]
    layer_kernel<<<H / 4, 256, 0, stream>>>((const ulonglong2*)actT,
                                            idxH, signsH,
                                            actT + (size_t)H * 2, thr);
    // layer 2: from actT[1] with idxH[1]/signsH[1]
    layer_kernel<<<H / 4, 256, 0, stream>>>((const ulonglong2*)(actT + (size_t)H * 2),
                                            idxH + (size_t)S * H * K,
                                            signsH + (size_t)S * H * K,
                                            actT + (size_t)2 * H * 2, thr);

    zero_out_kernel<<<(B * C + 255) / 256, 256, 0, stream>>>(out);
    final_kernel<<<H / 64, 128, 0, stream>>>(actT, wout, out);
}

// Round 3
// 186.018 us; speedup vs baseline: 1.5920x; 1.5920x over previous
//
#include <hip/hip_runtime.h>
#include <stdint.h>

#define B 128
#define F 8192
#define H 8192
#define S 4
#define K 32
#define L 3
#define C 100

// ---------------------------------------------------------------------------
// Pack x (B,F) float {0,1} -> xT[f] = 128-bit mask over b (2 u64 words).
// Block = 128 threads (thread = b), each block handles 64 consecutive f.
// float4 loads: 16 loads per thread instead of 64.
// ---------------------------------------------------------------------------
__global__ void pack_x_kernel(const float* __restrict__ x, uint64_t* __restrict__ xT) {
    const int b = threadIdx.x;           // 0..127
    const int f0 = blockIdx.x * 64;
    const float4* xr = (const float4*)(x + (size_t)b * F + f0);
    for (int j = 0; j < 16; ++j) {
        const float4 v = xr[j];
        const uint64_t m0 = __ballot(v.x > 0.5f);
        const uint64_t m1 = __ballot(v.y > 0.5f);
        const uint64_t m2 = __ballot(v.z > 0.5f);
        const uint64_t m3 = __ballot(v.w > 0.5f);
        if ((threadIdx.x & 63) == 0) {
            const int w = threadIdx.x >> 6;
            const int f = f0 + 4 * j;
            xT[(size_t)(f + 0) * 2 + w] = m0;
            xT[(size_t)(f + 1) * 2 + w] = m1;
            xT[(size_t)(f + 2) * 2 + w] = m2;
            xT[(size_t)(f + 3) * 2 + w] = m3;
        }
    }
}

__device__ __forceinline__ int load_threshold(const int* p) {
    // threshold is a tiny int; guard against the harness storing it as f32 bits
    int v = *p;
    if (v >= (1 << 23)) v = (int)__int_as_float(v);
    return v;
}

// ---------------------------------------------------------------------------
// One EISANI layer: prevT (Hprev x 128-bit) -> outT (H x 128-bit).
// One wave per neuron h; lane = batch (lane handles b=lane and b=lane+64).
// (unchanged from the passing round-2 version)
// ---------------------------------------------------------------------------
__global__ void layer_kernel(const ulonglong2* __restrict__ prevT,
                             const int* __restrict__ idx,
                             const float* __restrict__ signs,
                             uint64_t* __restrict__ outT,
                             const int* __restrict__ thrp) {
    const int lane = threadIdx.x & 63;
    const int h = blockIdx.x * 4 + (threadIdx.x >> 6);
    const int thr = load_threshold(thrp);

    bool f0 = false, f1 = false;
#pragma unroll
    for (int s = 0; s < S; ++s) {
        const int base = (s * H + h) * K;
        int packed = 0;
        if (lane < K) {
            const int ik = idx[base + lane];               // coalesced 128B
            const int neg = (signs[base + lane] < 0.0f) ? 1 : 0;
            packed = ik | (neg << 16);                     // ik < 8192 fits
        }
        int z0 = 0, z1 = 0;
#pragma unroll 8
        for (int k = 0; k < K; ++k) {
            const int p  = __builtin_amdgcn_readfirstlane(__shfl(packed, k, 64));
            const int ik = p & 0xFFFF;                     // wave-uniform (SGPR)
            const int sv = 1 - ((p >> 15) & 2);            // +1 / -1
            const ulonglong2 col = prevT[ik];              // uniform 16B load
            z0 += ((col.x >> lane) & 1ull) ? sv : 0;
            z1 += ((col.y >> lane) & 1ull) ? sv : 0;
        }
        f0 |= (z0 >= thr);
        f1 |= (z1 >= thr);
    }
    const uint64_t m0 = __ballot(f0);
    const uint64_t m1 = __ballot(f1);
    if (lane == 0) {
        outT[(size_t)h * 2]     = m0;
        outT[(size_t)h * 2 + 1] = m1;
    }
}

// ---------------------------------------------------------------------------
// Zero the output (harness poisons d_out before every launch).
// ---------------------------------------------------------------------------
__global__ void zero_out_kernel(float* __restrict__ out) {
    const int i = blockIdx.x * 256 + threadIdx.x;
    if (i < B * C) out[i] = 0.0f;
}

// ---------------------------------------------------------------------------
// out[b][c] = sum_l sum_h act[l][b][h] * wout[l][h][c], act in {0,1}.
// Wave = one b; lanes = c (acc in 2 VGPRs: c=lane, c=lane+64).
// Grid = 32 b-groups x NHC h-chunks; block = 256 (4 waves = 4 consecutive b).
// Per 64-h round: coalesced mask load -> ballot -> set-bit walk with
// coalesced wout-row loads. Tail: <=2 atomics per lane.
// ---------------------------------------------------------------------------
#define NHC 16
#define HCH (H / NHC)   // 512 h per chunk

__global__ void final_kernel(const uint64_t* __restrict__ actT,
                             const float* __restrict__ wout,
                             float* __restrict__ out) {
    const int lane = threadIdx.x & 63;
    const int wid  = threadIdx.x >> 6;          // 0..3
    const int hc   = blockIdx.x & (NHC - 1);
    const int bg   = blockIdx.x / NHC;          // 0..31
    const int b    = bg * 4 + wid;              // wave-uniform
    const int word = b >> 6;                    // uniform within wave
    const int bit  = b & 63;

    float acc0 = 0.0f, acc1 = 0.0f;
    const int c1 = 64 + lane;
    const bool c1v = (c1 < C);

    for (int l = 0; l < L; ++l) {
        const uint64_t* aT = actT + (size_t)l * H * 2;
        const float* wl = wout + (size_t)l * H * C;
        for (int r = 0; r < HCH / 64; ++r) {
            const int hbase = hc * HCH + r * 64;
            const uint64_t m = aT[(size_t)(hbase + lane) * 2 + word];
            uint64_t hm = __ballot((m >> bit) & 1ull);
            while (hm) {
                const int slot = __ffsll((unsigned long long)hm) - 1;
                hm &= hm - 1;
                const float* wr = wl + (size_t)(hbase + slot) * C;
                acc0 += wr[lane];
                if (c1v) acc1 += wr[c1];
            }
        }
    }
    atomicAdd(&out[b * C + lane], acc0);
    if (c1v) atomicAdd(&out[b * C + c1], acc1);
}

// ---------------------------------------------------------------------------
extern "C" void kernel_launch(void* const* d_in, const int* in_sizes, int n_in,
                              void* d_out, int out_size, void* d_ws, size_t ws_size,
                              hipStream_t stream) {
    const float* x      = (const float*)d_in[0];   // (B,F)
    const float* signs0 = (const float*)d_in[1];   // (S,H,K)
    const float* signsH = (const float*)d_in[2];   // (L-1,S,H,K)
    const float* wout   = (const float*)d_in[3];   // (L,H,C)
    const int*   idx0   = (const int*)d_in[4];     // (S,H,K)
    const int*   idxH   = (const int*)d_in[5];     // (L-1,S,H,K)
    const int*   thr    = (const int*)d_in[6];     // scalar
    float* out = (float*)d_out;                    // (B,C)

    // Workspace: xT (F*2 u64) then actT (L*H*2 u64) -> 512 KiB total.
    uint64_t* xT   = (uint64_t*)d_ws;
    uint64_t* actT = xT + (size_t)F * 2;

    pack_x_kernel<<<F / 64, 128, 0, stream>>>(x, xT);

    // layer 0: from xT with idx0/signs0
    layer_kernel<<<H / 4, 256, 0, stream>>>((const ulonglong2*)xT, idx0, signs0,
                                            actT, thr);
    // layer 1: from actT[0] with idxH[0]/signsH[0]
    layer_kernel<<<H / 4, 256, 0, stream>>>((const ulonglong2*)actT,
                                            idxH, signsH,
                                            actT + (size_t)H * 2, thr);
    // layer 2: from actT[1] with idxH[1]/signsH[1]
    layer_kernel<<<H / 4, 256, 0, stream>>>((const ulonglong2*)(actT + (size_t)H * 2),
                                            idxH + (size_t)S * H * K,
                                            signsH + (size_t)S * H * K,
                                            actT + (size_t)2 * H * 2, thr);

    zero_out_kernel<<<(B * C + 255) / 256, 256, 0, stream>>>(out);
    final_kernel<<<32 * NHC, 256, 0, stream>>>(actT, wout, out);
}